// Round 16
// baseline (331.298 us; speedup 1.0000x reference)
//
#include <hip/hip_runtime.h>
#include <hip/hip_bf16.h>

#define HEADS 4

typedef __attribute__((ext_vector_type(4))) float f32x4;
typedef __attribute__((ext_vector_type(8))) short s16x8;

// ---------------- bf16 helpers ----------------
__device__ __forceinline__ float u2f(unsigned short u) {
    return __uint_as_float(((unsigned)u) << 16);
}
__device__ __forceinline__ unsigned short rne(float v) {
    unsigned b = __float_as_uint(v);
    return (unsigned short)((b + 0x7FFF + ((b >> 16) & 1)) >> 16);
}
__device__ __forceinline__ float ld1(const float* p) { return *p; }
__device__ __forceinline__ float ld1(const __hip_bfloat16* p) {
    return u2f(*reinterpret_cast<const unsigned short*>(p));
}
__device__ __forceinline__ float2 ld2(const float* p) { return *reinterpret_cast<const float2*>(p); }
__device__ __forceinline__ float2 ld2(const __hip_bfloat16* p) {
    ushort2 u = *reinterpret_cast<const ushort2*>(p);
    return make_float2(u2f(u.x), u2f(u.y));
}
__device__ __forceinline__ float4 ld4(const float* p) { return *reinterpret_cast<const float4*>(p); }
__device__ __forceinline__ float4 ld4(const __hip_bfloat16* p) {
    ushort4 u = *reinterpret_cast<const ushort4*>(p);
    return make_float4(u2f(u.x), u2f(u.y), u2f(u.z), u2f(u.w));
}
__device__ __forceinline__ void st1(float* p, float v) { *p = v; }
__device__ __forceinline__ void st1(__hip_bfloat16* p, float v) {
    *reinterpret_cast<unsigned short*>(p) = rne(v);
}
__device__ __forceinline__ void st2(float* p, float a, float b) {
    *reinterpret_cast<float2*>(p) = make_float2(a, b);
}
__device__ __forceinline__ void st2(__hip_bfloat16* p, float a, float b) {
    *reinterpret_cast<ushort2*>(p) = make_ushort2(rne(a), rne(b));
}
__device__ __forceinline__ void st4(float* p, float4 v) { *reinterpret_cast<float4*>(p) = v; }
__device__ __forceinline__ void st4(__hip_bfloat16* p, float4 v) {
    *reinterpret_cast<ushort4*>(p) = make_ushort4(rne(v.x), rne(v.y), rne(v.z), rne(v.w));
}

// ---------------- inline int64-layout detection ----------------
__device__ __forceinline__ int detect64(const int* __restrict__ e) {
    return ((e[1] | e[3] | e[5] | e[7]) == 0) ? 1 : 0;
}
__device__ __forceinline__ int edge_elem(const int* e, size_t idx, int is64) {
    return is64 ? e[2 * idx] : e[idx];
}

// ---------------- CSR build ----------------
__global__ void deg_kernel(const int* __restrict__ eidx, int* __restrict__ deg, int E, int N) {
    int e = blockIdx.x * blockDim.x + threadIdx.x;
    if (e < E) {
        int is64 = detect64(eidx);
        int d = edge_elem(eidx, (size_t)E + e, is64);
        if ((unsigned)d < (unsigned)N) atomicAdd(&deg[d], 1);
    }
}

__global__ void reduce_kernel(const int* __restrict__ deg, int* __restrict__ bsum, int n) {
    __shared__ int sdata[256];
    int base = blockIdx.x * 1024;
    int t = threadIdx.x;
    int v = 0;
#pragma unroll
    for (int j = 0; j < 4; ++j) {
        int i = base + t + j * 256;
        if (i < n) v += deg[i];
    }
    sdata[t] = v;
    __syncthreads();
    for (int off = 128; off > 0; off >>= 1) {
        if (t < off) sdata[t] += sdata[t + off];
        __syncthreads();
    }
    if (t == 0) bsum[blockIdx.x] = sdata[0];
}

__global__ void scan_bsum_kernel(const int* __restrict__ bsum, int* __restrict__ boff,
                                 int nb, int* __restrict__ totalp) {
    int lane = threadIdx.x;
    int carry = 0;
    for (int base = 0; base < nb; base += 64) {
        int i = base + lane;
        int v = (i < nb) ? bsum[i] : 0;
        int inc = v;
        for (int off = 1; off < 64; off <<= 1) {
            int tt = __shfl_up(inc, off);
            if (lane >= off) inc += tt;
        }
        if (i < nb) boff[i] = carry + inc - v;
        carry += __shfl(inc, 63);
    }
    if (lane == 0) *totalp = carry;
}

__global__ void block_scan_kernel(const int* __restrict__ deg, const int* __restrict__ boff,
                                  int* __restrict__ rowptr, int* __restrict__ cursor, int n) {
    __shared__ int wsum[4];
    int base = blockIdx.x * 1024;
    int t = threadIdx.x;
    int lane = t & 63, w = t >> 6;
    int v[4];
    int lsum = 0;
#pragma unroll
    for (int j = 0; j < 4; ++j) {
        int i = base + t * 4 + j;
        v[j] = (i < n) ? deg[i] : 0;
        lsum += v[j];
    }
    int inc = lsum;
    for (int off = 1; off < 64; off <<= 1) {
        int tt = __shfl_up(inc, off);
        if (lane >= off) inc += tt;
    }
    if (lane == 63) wsum[w] = inc;
    __syncthreads();
    int woff = 0;
    for (int i = 0; i < w; ++i) woff += wsum[i];
    int ex = boff[blockIdx.x] + woff + inc - lsum;
#pragma unroll
    for (int j = 0; j < 4; ++j) {
        int i = base + t * 4 + j;
        if (i < n) { rowptr[i] = ex; cursor[i] = ex; }
        ex += v[j];
    }
}

__global__ void scatter_kernel(const int* __restrict__ eidx, int* __restrict__ cursor,
                               int* __restrict__ csr_src, int E, int N) {
    int e = blockIdx.x * blockDim.x + threadIdx.x;
    if (e < E) {
        int is64 = detect64(eidx);
        int s = edge_elem(eidx, (size_t)e, is64);
        int d = edge_elem(eidx, (size_t)E + e, is64);
        if ((unsigned)d < (unsigned)N && (unsigned)s < (unsigned)N) {
            int pos = atomicAdd(&cursor[d], 1);
            csr_src[pos] = s;
        }
    }
}

// ---------------- prep0: Bt3, BtF (=W1@W2 folded), bias12, proj1, proj3 ----------------
__global__ void prep0_kernel(const float* __restrict__ W1, const float* __restrict__ W2,
                             const float* __restrict__ W3, const float* __restrict__ b1,
                             const float* __restrict__ a1s, const float* __restrict__ a1d,
                             const float* __restrict__ a3s, const float* __restrict__ a3d,
                             __hip_bfloat16* __restrict__ Bt3, __hip_bfloat16* __restrict__ BtF,
                             float* __restrict__ bias12,
                             float* __restrict__ ps1, float* __restrict__ pd1,
                             float* __restrict__ ps3, float* __restrict__ pd3) {
    int b = blockIdx.x, t = threadIdx.x;
    if (b < 128) {  // Bt3 [64][512]
        int idx = b * 256 + t;
        int c = idx >> 9, r = idx & 511;
        int h = r >> 7, kk = r & 127;
        st1(&Bt3[idx], W3[(size_t)kk * 256 + h * 64 + c] * 0.25f);
        return;
    }
    b -= 128;
    if (b < 128) {  // BtF [128][256]
        int idx = b * 256 + t;
        int m = idx >> 8, k = idx & 255;
        int h = k >> 6, kin = k & 63;
        float acc = 0.f;
        for (int c = 0; c < 64; ++c)
            acc += W1[(size_t)kin * 256 + h * 64 + c] * W2[(size_t)(h * 64 + c) * 128 + m];
        st1(&BtF[idx], acc);
        return;
    }
    b -= 128;
    if (b < 1) {  // bias12
        if (t < 128) {
            float acc = 0.f;
            for (int j = 0; j < 256; ++j) acc += b1[j] * W2[(size_t)j * 128 + t];
            bias12[t] = acc;
        }
        return;
    }
    b -= 1;
    if (b < 1) {  // proj1
        int h = t >> 6, k = t & 63;
        float ss = 0.f, sd = 0.f;
        for (int c = 0; c < 64; ++c) {
            float w = W1[(size_t)k * 256 + h * 64 + c];
            ss += w * a1s[h * 64 + c];
            sd += w * a1d[h * 64 + c];
        }
        ps1[t] = ss;
        pd1[t] = sd;
        return;
    }
    b -= 1;
    if (b < 2) {  // proj3
        int idx = b * 256 + t;
        int h = idx >> 7, k = idx & 127;
        float ss = 0.f, sd = 0.f;
        for (int c = 0; c < 64; ++c) {
            float w = W3[(size_t)k * 256 + h * 64 + c];
            ss += w * a3s[h * 64 + c];
            sd += w * a3d[h * 64 + c];
        }
        ps3[idx] = ss;
        pd3[idx] = sd;
        return;
    }
}

// ---------------- x -> bf16 conversion + fused L1 logits ----------------
__global__ void xconv_alx_kernel(const float* __restrict__ x, const float* __restrict__ ps1,
                                 const float* __restrict__ pd1, __hip_bfloat16* __restrict__ xb,
                                 float* __restrict__ als, float* __restrict__ ald, int n8) {
    int i = blockIdx.x * blockDim.x + threadIdx.x;
    if (i >= n8) return;
    int r = i >> 3, sub = i & 7;
    int cbase = sub * 8;
    float4 a = *reinterpret_cast<const float4*>(&x[(size_t)i * 8]);
    float4 c = *reinterpret_cast<const float4*>(&x[(size_t)i * 8 + 4]);
    st4(&xb[(size_t)i * 8], a);
    st4(&xb[(size_t)i * 8 + 4], c);
    float ss[4], sd[4];
#pragma unroll
    for (int h = 0; h < 4; ++h) {
        float4 s0 = *reinterpret_cast<const float4*>(&ps1[h * 64 + cbase]);
        float4 s1 = *reinterpret_cast<const float4*>(&ps1[h * 64 + cbase + 4]);
        float4 d0 = *reinterpret_cast<const float4*>(&pd1[h * 64 + cbase]);
        float4 d1 = *reinterpret_cast<const float4*>(&pd1[h * 64 + cbase + 4]);
        ss[h] = a.x * s0.x + a.y * s0.y + a.z * s0.z + a.w * s0.w
              + c.x * s1.x + c.y * s1.y + c.z * s1.z + c.w * s1.w;
        sd[h] = a.x * d0.x + a.y * d0.y + a.z * d0.z + a.w * d0.w
              + c.x * d1.x + c.y * d1.y + c.z * d1.z + c.w * d1.w;
    }
#pragma unroll
    for (int off = 1; off < 8; off <<= 1) {
#pragma unroll
        for (int h = 0; h < 4; ++h) {
            ss[h] += __shfl_xor(ss[h], off);
            sd[h] += __shfl_xor(sd[h], off);
        }
    }
    if (sub == 0) {
        *reinterpret_cast<float4*>(&als[(size_t)r * 4]) = make_float4(ss[0], ss[1], ss[2], ss[3]);
        *reinterpret_cast<float4*>(&ald[(size_t)r * 4]) = make_float4(sd[0], sd[1], sd[2], sd[3]);
    }
}

// ---------------- fused gather (pre-agg): shuffle-broadcast weights, one wave/node (R14 shape) ----------------
template <int K, typename TIN, typename TOUT>
__global__ void gather_pre_kernel(const TIN* __restrict__ x, const float* __restrict__ als,
                                  const float* __restrict__ ald, const int* __restrict__ rowptr,
                                  const int* __restrict__ csr, TOUT* __restrict__ agg, int N) {
    constexpr int V = K / 64;  // 1 (K=64) or 2 (K=128)
    int wave = (blockIdx.x * blockDim.x + threadIdx.x) >> 6;
    int lane = threadIdx.x & 63;
    if (wave >= N) return;
    int h4 = lane & 3, e4 = lane >> 2;
    float aldv = ald[wave * 4 + h4];
    float s0 = 0.f, s1 = 0.f, s2 = 0.f, s3 = 0.f;
    float acc[4][V] = {};
    int beg = rowptr[wave], end = rowptr[wave + 1];
    for (int kc = beg; kc < end; kc += 16) {
        int cnt = end - kc;
        if (cnt > 16) cnt = 16;
        int j = kc + e4;
        int src = csr[(j < end) ? j : beg];
        float e = als[src * 4 + h4] + aldv;
        e = fmaxf(e, 0.2f * e);
        float myw = __expf(e);
        if (cnt == 16) {
            int sj[16];
#pragma unroll
            for (int jj = 0; jj < 16; ++jj) sj[jj] = __shfl(src, jj * 4);
            if (V == 1) {
                float pv[16];
#pragma unroll
                for (int jj = 0; jj < 16; ++jj) pv[jj] = ld1(&x[(size_t)sj[jj] * K + lane]);
#pragma unroll
                for (int jj = 0; jj < 16; ++jj) {
                    float w0 = __shfl(myw, jj * 4 + 0), w1 = __shfl(myw, jj * 4 + 1);
                    float w2 = __shfl(myw, jj * 4 + 2), w3 = __shfl(myw, jj * 4 + 3);
                    s0 += w0; s1 += w1; s2 += w2; s3 += w3;
                    acc[0][0] += w0 * pv[jj]; acc[1][0] += w1 * pv[jj];
                    acc[2][0] += w2 * pv[jj]; acc[3][0] += w3 * pv[jj];
                }
            } else {
                float2 pv[16];
#pragma unroll
                for (int jj = 0; jj < 16; ++jj) pv[jj] = ld2(&x[(size_t)sj[jj] * K + lane * 2]);
#pragma unroll
                for (int jj = 0; jj < 16; ++jj) {
                    float w0 = __shfl(myw, jj * 4 + 0), w1 = __shfl(myw, jj * 4 + 1);
                    float w2 = __shfl(myw, jj * 4 + 2), w3 = __shfl(myw, jj * 4 + 3);
                    s0 += w0; s1 += w1; s2 += w2; s3 += w3;
                    acc[0][0] += w0 * pv[jj].x; acc[0][1] += w0 * pv[jj].y;
                    acc[1][0] += w1 * pv[jj].x; acc[1][1] += w1 * pv[jj].y;
                    acc[2][0] += w2 * pv[jj].x; acc[2][1] += w2 * pv[jj].y;
                    acc[3][0] += w3 * pv[jj].x; acc[3][1] += w3 * pv[jj].y;
                }
            }
        } else {
            for (int jj = 0; jj < cnt; ++jj) {
                int sjj = __shfl(src, jj * 4);
                float w0 = __shfl(myw, jj * 4 + 0), w1 = __shfl(myw, jj * 4 + 1);
                float w2 = __shfl(myw, jj * 4 + 2), w3 = __shfl(myw, jj * 4 + 3);
                s0 += w0; s1 += w1; s2 += w2; s3 += w3;
                if (V == 1) {
                    float v = ld1(&x[(size_t)sjj * K + lane]);
                    acc[0][0] += w0 * v; acc[1][0] += w1 * v;
                    acc[2][0] += w2 * v; acc[3][0] += w3 * v;
                } else {
                    float2 v = ld2(&x[(size_t)sjj * K + lane * 2]);
                    acc[0][0] += w0 * v.x; acc[0][1] += w0 * v.y;
                    acc[1][0] += w1 * v.x; acc[1][1] += w1 * v.y;
                    acc[2][0] += w2 * v.x; acc[2][1] += w2 * v.y;
                    acc[3][0] += w3 * v.x; acc[3][1] += w3 * v.y;
                }
            }
        }
    }
    float inv[4] = {1.f / (s0 + 1e-16f), 1.f / (s1 + 1e-16f),
                    1.f / (s2 + 1e-16f), 1.f / (s3 + 1e-16f)};
    size_t o = (size_t)wave * 4 * K;
#pragma unroll
    for (int h = 0; h < 4; ++h) {
        if (V == 1) {
            st1(&agg[o + h * K + lane], acc[h][0] * inv[h]);
        } else {
            st2(&agg[o + h * K + lane * 2], acc[h][0] * inv[h], acc[h][1] * inv[h]);
        }
    }
}

// ---------------- fused gather (post-GEMM L2) + L3 logits: shuffle weights, one wave/node ----------------
template <typename TIN, typename TOUT>
__global__ void gather_post32_alx_kernel(
    const TIN* __restrict__ h2, const float* __restrict__ als,
    const float* __restrict__ ald, const int* __restrict__ rowptr,
    const int* __restrict__ csr, const float* __restrict__ bias,
    const float* __restrict__ ps3, const float* __restrict__ pd3,
    TOUT* __restrict__ outp,
    float* __restrict__ als3, float* __restrict__ ald3, int N) {
    int wave = (blockIdx.x * blockDim.x + threadIdx.x) >> 6;
    int lane = threadIdx.x & 63;
    if (wave >= N) return;
    int h4 = lane & 3, e4 = lane >> 2;
    int hh = lane >> 4, l16 = lane & 15;
    float aldv = ald[wave * 4 + h4];
    float s = 0.f, a0 = 0.f, a1 = 0.f;
    int beg = rowptr[wave], end = rowptr[wave + 1];
    for (int kc = beg; kc < end; kc += 16) {
        int cnt = end - kc;
        if (cnt > 16) cnt = 16;
        int j = kc + e4;
        int src = csr[(j < end) ? j : beg];
        float e = als[src * 4 + h4] + aldv;
        e = fmaxf(e, 0.2f * e);
        float myw = __expf(e);
        if (cnt == 16) {
            int sj[16];
#pragma unroll
            for (int jj = 0; jj < 16; ++jj) sj[jj] = __shfl(src, jj * 4);
            float2 pv[16];
#pragma unroll
            for (int jj = 0; jj < 16; ++jj)
                pv[jj] = ld2(&h2[(size_t)sj[jj] * 128 + hh * 32 + l16 * 2]);
#pragma unroll
            for (int jj = 0; jj < 16; ++jj) {
                float w = __shfl(myw, jj * 4 + hh);
                s += w;
                a0 += w * pv[jj].x;
                a1 += w * pv[jj].y;
            }
        } else {
            for (int jj = 0; jj < cnt; ++jj) {
                int sjj = __shfl(src, jj * 4);
                float w = __shfl(myw, jj * 4 + hh);
                s += w;
                float2 v = ld2(&h2[(size_t)sjj * 128 + hh * 32 + l16 * 2]);
                a0 += w * v.x;
                a1 += w * v.y;
            }
        }
    }
    float inv = 1.f / (s + 1e-16f);
    int c = hh * 32 + l16 * 2;
    float v0 = a0 * inv + bias[c];
    float v1 = a1 * inv + bias[c + 1];
    st2(&outp[(size_t)wave * 128 + c], v0, v1);

    // ---- layer-3 logits in-register ----
    float sArr[4], dArr[4];
#pragma unroll
    for (int h = 0; h < 4; ++h) {
        float2 vs = *reinterpret_cast<const float2*>(&ps3[h * 128 + c]);
        float2 vd = *reinterpret_cast<const float2*>(&pd3[h * 128 + c]);
        sArr[h] = v0 * vs.x + v1 * vs.y;
        dArr[h] = v0 * vd.x + v1 * vd.y;
    }
#pragma unroll
    for (int off = 1; off < 64; off <<= 1) {
#pragma unroll
        for (int h = 0; h < 4; ++h) {
            sArr[h] += __shfl_xor(sArr[h], off);
            dArr[h] += __shfl_xor(dArr[h], off);
        }
    }
    if (lane < 4) {
        float os = (lane == 0) ? sArr[0] : (lane == 1) ? sArr[1] : (lane == 2) ? sArr[2] : sArr[3];
        float od = (lane == 0) ? dArr[0] : (lane == 1) ? dArr[1] : (lane == 2) ? dArr[2] : dArr[3];
        als3[wave * 4 + lane] = os;
        ald3[wave * 4 + lane] = od;
    }
}

// ---------------- MFMA GEMM (BM=128 BN=64 BK=32), optional fused col-dot logits ----------------
template <typename TOUT>
__global__ __launch_bounds__(256) void mfma_gemm_kernel(
    const __hip_bfloat16* __restrict__ A, int lda, int aSel,
    const __hip_bfloat16* __restrict__ Bt,
    TOUT* __restrict__ O, int ldo,
    const float* __restrict__ bias,
    const float* __restrict__ a2s, const float* __restrict__ a2d,
    float* __restrict__ oals, float* __restrict__ oald,
    int N, int K) {
    __shared__ __hip_bfloat16 As[128][40];
    __shared__ __hip_bfloat16 Bs[64][40];
    int col0 = blockIdx.x * 64;
    int row0 = blockIdx.y * 128;
    int aOff = aSel ? col0 : 0;
    int tid = threadIdx.x;
    int wv = tid >> 6, lane = tid & 63;
    int g = lane >> 4, l16 = lane & 15;
    f32x4 acc[2][4] = {};

    for (int k0 = 0; k0 < K; k0 += 32) {
#pragma unroll
        for (int i = 0; i < 2; ++i) {
            int idx = tid + i * 256;
            int r = idx >> 2, h4 = idx & 3;
            int gr = row0 + r;
            uint4 v = make_uint4(0, 0, 0, 0);
            if (gr < N) v = *reinterpret_cast<const uint4*>(&A[(size_t)gr * lda + aOff + k0 + h4 * 8]);
            *reinterpret_cast<uint4*>(&As[r][h4 * 8]) = v;
        }
        {
            int r = tid >> 2, h4 = tid & 3;
            uint4 v = *reinterpret_cast<const uint4*>(&Bt[(size_t)(col0 + r) * K + k0 + h4 * 8]);
            *reinterpret_cast<uint4*>(&Bs[r][h4 * 8]) = v;
        }
        __syncthreads();
        s16x8 af[2], bf[4];
#pragma unroll
        for (int m = 0; m < 2; ++m)
            af[m] = *reinterpret_cast<const s16x8*>(&As[wv * 32 + m * 16 + l16][g * 8]);
#pragma unroll
        for (int n = 0; n < 4; ++n)
            bf[n] = *reinterpret_cast<const s16x8*>(&Bs[n * 16 + l16][g * 8]);
#pragma unroll
        for (int m = 0; m < 2; ++m)
#pragma unroll
            for (int n = 0; n < 4; ++n)
                acc[m][n] = __builtin_amdgcn_mfma_f32_16x16x32_bf16(af[m], bf[n], acc[m][n], 0, 0, 0);
        __syncthreads();
    }
#pragma unroll
    for (int m = 0; m < 2; ++m) {
#pragma unroll
        for (int rr = 0; rr < 4; ++rr) {
            int row = row0 + wv * 32 + m * 16 + g * 4 + rr;
            float vv[4];
#pragma unroll
            for (int n = 0; n < 4; ++n) {
                vv[n] = acc[m][n][rr];
                if (bias) vv[n] += bias[col0 + n * 16 + l16];
            }
            if (row < N) {
#pragma unroll
                for (int n = 0; n < 4; ++n)
                    st1(&O[(size_t)row * ldo + col0 + n * 16 + l16], vv[n]);
            }
            if (oals) {
                float ts0 = vv[0] * a2s[col0 + l16]      + vv[1] * a2s[col0 + 16 + l16];
                float ts1 = vv[2] * a2s[col0 + 32 + l16] + vv[3] * a2s[col0 + 48 + l16];
                float td0 = vv[0] * a2d[col0 + l16]      + vv[1] * a2d[col0 + 16 + l16];
                float td1 = vv[2] * a2d[col0 + 32 + l16] + vv[3] * a2d[col0 + 48 + l16];
#pragma unroll
                for (int off = 1; off < 16; off <<= 1) {
                    ts0 += __shfl_xor(ts0, off); ts1 += __shfl_xor(ts1, off);
                    td0 += __shfl_xor(td0, off); td1 += __shfl_xor(td1, off);
                }
                if (l16 == 0 && row < N) {
                    int hb = col0 >> 5;  // heads 2x, 2x+1
                    oals[(size_t)row * 4 + hb]     = ts0;
                    oals[(size_t)row * 4 + hb + 1] = ts1;
                    oald[(size_t)row * 4 + hb]     = td0;
                    oald[(size_t)row * 4 + hb + 1] = td1;
                }
            }
        }
    }
}

// ---------------- launch ----------------
extern "C" void kernel_launch(void* const* d_in, const int* in_sizes, int n_in,
                              void* d_out, int out_size, void* d_ws, size_t ws_size,
                              hipStream_t stream) {
    const float* x      = (const float*)d_in[0];
    const int*   eidx   = (const int*)d_in[1];
    const float* W1     = (const float*)d_in[2];
    const float* a1_src = (const float*)d_in[3];
    const float* a1_dst = (const float*)d_in[4];
    const float* b1     = (const float*)d_in[5];
    const float* W2     = (const float*)d_in[6];
    const float* a2_src = (const float*)d_in[7];
    const float* a2_dst = (const float*)d_in[8];
    const float* b2     = (const float*)d_in[9];
    const float* W3     = (const float*)d_in[10];
    const float* a3_src = (const float*)d_in[11];
    const float* a3_dst = (const float*)d_in[12];
    const float* b3     = (const float*)d_in[13];
    float* out = (float*)d_out;

    const int N = in_sizes[0] / 64;      // 50000
    const int E = in_sizes[1] / 2;       // 800000
    const int NB = (N + 1023) / 1024;

    // ---- workspace ----
    int* rowptr = (int*)d_ws;
    int* deg    = rowptr + (N + 1);
    int* cursor = deg + N;
    int* csr    = cursor + N;
    int* bsum   = csr + E;
    int* boff   = bsum + NB;
    uintptr_t pa = (uintptr_t)(boff + NB);
    pa = (pa + 255) & ~(uintptr_t)255;
    float* als  = (float*)pa;                       // N*4
    float* ald  = als + (size_t)N * 4;              // N*4
    float* als3 = ald + (size_t)N * 4;              // N*4
    float* ald3 = als3 + (size_t)N * 4;             // N*4
    float* ps1  = ald3 + (size_t)N * 4;             // 256
    float* pd1  = ps1 + 256;                        // 256
    float* ps3  = pd1 + 256;                        // 512
    float* pd3  = ps3 + 512;                        // 512
    float* bias12 = pd3 + 512;                      // 128
    __hip_bfloat16* Bt3 = (__hip_bfloat16*)(bias12 + 128);  // 64*512
    __hip_bfloat16* BtF = Bt3 + 64 * 512;                   // 128*256
    uintptr_t pf = (uintptr_t)(BtF + 128 * 256);
    pf = (pf + 255) & ~(uintptr_t)255;
    float* F    = (float*)pf;

    // arena (float units): xb 32N | agg1b 128N | h2b 64N | out2b 64N | agg3 256N = 544N
    __hip_bfloat16* xb    = (__hip_bfloat16*)F;
    __hip_bfloat16* agg1b = (__hip_bfloat16*)(F + (size_t)N * 32);
    __hip_bfloat16* h2b   = (__hip_bfloat16*)(F + (size_t)N * 160);
    __hip_bfloat16* out2b = (__hip_bfloat16*)(F + (size_t)N * 224);
    __hip_bfloat16* agg3  = (__hip_bfloat16*)(F + (size_t)N * 288);

    // ---- CSR build ----
    hipMemsetAsync(deg, 0, (size_t)N * sizeof(int), stream);
    deg_kernel<<<(E + 255) / 256, 256, 0, stream>>>(eidx, deg, E, N);
    reduce_kernel<<<NB, 256, 0, stream>>>(deg, bsum, N);
    scan_bsum_kernel<<<1, 64, 0, stream>>>(bsum, boff, NB, rowptr + N);
    block_scan_kernel<<<NB, 256, 0, stream>>>(deg, boff, rowptr, cursor, N);
    scatter_kernel<<<(E + 255) / 256, 256, 0, stream>>>(eidx, cursor, csr, E, N);

    // ---- prep0 (weights/proj) then x-conv + fused L1 logits ----
    prep0_kernel<<<128 + 128 + 1 + 1 + 2, 256, 0, stream>>>(
        W1, W2, W3, b1, a1_src, a1_dst, a3_src, a3_dst,
        Bt3, BtF, bias12, ps1, pd1, ps3, pd3);
    const int n8 = N * 8;
    xconv_alx_kernel<<<(n8 + 255) / 256, 256, 0, stream>>>(x, ps1, pd1, xb, als, ald, n8);

    const int aggBlocks = (N + 3) / 4;  // one wave per node, HW-scheduled
    const int rowB128   = (N + 127) / 128;

    // ---- layer 1 gather + fused L1L2-GEMM (with fused L2 logits) ----
    gather_pre_kernel<64, __hip_bfloat16, __hip_bfloat16><<<aggBlocks, 256, 0, stream>>>(
        xb, als, ald, rowptr, csr, agg1b, N);
    mfma_gemm_kernel<__hip_bfloat16><<<dim3(2, rowB128), 256, 0, stream>>>(
        agg1b, 256, 0, BtF, h2b, 128, bias12, a2_src, a2_dst, als, ald, N, 256);

    // ---- layer 2: gather (fused layer-3 logits) ----
    gather_post32_alx_kernel<__hip_bfloat16, __hip_bfloat16><<<aggBlocks, 256, 0, stream>>>(
        h2b, als, ald, rowptr, csr, b2, ps3, pd3, out2b, als3, ald3, N);

    // ---- layer 3: gather + stacked GEMM (mean folded) ----
    gather_pre_kernel<128, __hip_bfloat16, __hip_bfloat16><<<aggBlocks, 256, 0, stream>>>(
        out2b, als3, ald3, rowptr, csr, agg3, N);
    mfma_gemm_kernel<float><<<dim3(1, rowB128), 256, 0, stream>>>(
        agg3, 512, 0, Bt3, out, 64, b3, nullptr, nullptr, nullptr, nullptr, N, 512);
}

// Round 17
// 320.114 us; speedup vs baseline: 1.0349x; 1.0349x over previous
//
#include <hip/hip_runtime.h>
#include <hip/hip_bf16.h>

#define HEADS 4

typedef __attribute__((ext_vector_type(4))) float f32x4;
typedef __attribute__((ext_vector_type(8))) short s16x8;

// ---------------- bf16 helpers ----------------
__device__ __forceinline__ float u2f(unsigned short u) {
    return __uint_as_float(((unsigned)u) << 16);
}
__device__ __forceinline__ unsigned short rne(float v) {
    unsigned b = __float_as_uint(v);
    return (unsigned short)((b + 0x7FFF + ((b >> 16) & 1)) >> 16);
}
__device__ __forceinline__ float ld1(const float* p) { return *p; }
__device__ __forceinline__ float ld1(const __hip_bfloat16* p) {
    return u2f(*reinterpret_cast<const unsigned short*>(p));
}
__device__ __forceinline__ float2 ld2(const float* p) { return *reinterpret_cast<const float2*>(p); }
__device__ __forceinline__ float2 ld2(const __hip_bfloat16* p) {
    ushort2 u = *reinterpret_cast<const ushort2*>(p);
    return make_float2(u2f(u.x), u2f(u.y));
}
__device__ __forceinline__ float4 ld4(const float* p) { return *reinterpret_cast<const float4*>(p); }
__device__ __forceinline__ float4 ld4(const __hip_bfloat16* p) {
    ushort4 u = *reinterpret_cast<const ushort4*>(p);
    return make_float4(u2f(u.x), u2f(u.y), u2f(u.z), u2f(u.w));
}
__device__ __forceinline__ void st1(float* p, float v) { *p = v; }
__device__ __forceinline__ void st1(__hip_bfloat16* p, float v) {
    *reinterpret_cast<unsigned short*>(p) = rne(v);
}
__device__ __forceinline__ void st2(float* p, float a, float b) {
    *reinterpret_cast<float2*>(p) = make_float2(a, b);
}
__device__ __forceinline__ void st2(__hip_bfloat16* p, float a, float b) {
    *reinterpret_cast<ushort2*>(p) = make_ushort2(rne(a), rne(b));
}
__device__ __forceinline__ void st4(float* p, float4 v) { *reinterpret_cast<float4*>(p) = v; }
__device__ __forceinline__ void st4(__hip_bfloat16* p, float4 v) {
    *reinterpret_cast<ushort4*>(p) = make_ushort4(rne(v.x), rne(v.y), rne(v.z), rne(v.w));
}

// ---------------- inline int64-layout detection ----------------
__device__ __forceinline__ int detect64(const int* __restrict__ e) {
    return ((e[1] | e[3] | e[5] | e[7]) == 0) ? 1 : 0;
}
__device__ __forceinline__ int edge_elem(const int* e, size_t idx, int is64) {
    return is64 ? e[2 * idx] : e[idx];
}

// ---------------- CSR build ----------------
__global__ void deg_kernel(const int* __restrict__ eidx, int* __restrict__ deg, int E, int N) {
    int e = blockIdx.x * blockDim.x + threadIdx.x;
    if (e < E) {
        int is64 = detect64(eidx);
        int d = edge_elem(eidx, (size_t)E + e, is64);
        if ((unsigned)d < (unsigned)N) atomicAdd(&deg[d], 1);
    }
}

__global__ void reduce_kernel(const int* __restrict__ deg, int* __restrict__ bsum, int n) {
    __shared__ int sdata[256];
    int base = blockIdx.x * 1024;
    int t = threadIdx.x;
    int v = 0;
#pragma unroll
    for (int j = 0; j < 4; ++j) {
        int i = base + t + j * 256;
        if (i < n) v += deg[i];
    }
    sdata[t] = v;
    __syncthreads();
    for (int off = 128; off > 0; off >>= 1) {
        if (t < off) sdata[t] += sdata[t + off];
        __syncthreads();
    }
    if (t == 0) bsum[blockIdx.x] = sdata[0];
}

__global__ void scan_bsum_kernel(const int* __restrict__ bsum, int* __restrict__ boff,
                                 int nb, int* __restrict__ totalp) {
    int lane = threadIdx.x;
    int carry = 0;
    for (int base = 0; base < nb; base += 64) {
        int i = base + lane;
        int v = (i < nb) ? bsum[i] : 0;
        int inc = v;
        for (int off = 1; off < 64; off <<= 1) {
            int tt = __shfl_up(inc, off);
            if (lane >= off) inc += tt;
        }
        if (i < nb) boff[i] = carry + inc - v;
        carry += __shfl(inc, 63);
    }
    if (lane == 0) *totalp = carry;
}

__global__ void block_scan_kernel(const int* __restrict__ deg, const int* __restrict__ boff,
                                  int* __restrict__ rowptr, int* __restrict__ cursor, int n) {
    __shared__ int wsum[4];
    int base = blockIdx.x * 1024;
    int t = threadIdx.x;
    int lane = t & 63, w = t >> 6;
    int v[4];
    int lsum = 0;
#pragma unroll
    for (int j = 0; j < 4; ++j) {
        int i = base + t * 4 + j;
        v[j] = (i < n) ? deg[i] : 0;
        lsum += v[j];
    }
    int inc = lsum;
    for (int off = 1; off < 64; off <<= 1) {
        int tt = __shfl_up(inc, off);
        if (lane >= off) inc += tt;
    }
    if (lane == 63) wsum[w] = inc;
    __syncthreads();
    int woff = 0;
    for (int i = 0; i < w; ++i) woff += wsum[i];
    int ex = boff[blockIdx.x] + woff + inc - lsum;
#pragma unroll
    for (int j = 0; j < 4; ++j) {
        int i = base + t * 4 + j;
        if (i < n) { rowptr[i] = ex; cursor[i] = ex; }
        ex += v[j];
    }
}

__global__ void scatter_kernel(const int* __restrict__ eidx, int* __restrict__ cursor,
                               int* __restrict__ csr_src, int E, int N) {
    int e = blockIdx.x * blockDim.x + threadIdx.x;
    if (e < E) {
        int is64 = detect64(eidx);
        int s = edge_elem(eidx, (size_t)e, is64);
        int d = edge_elem(eidx, (size_t)E + e, is64);
        if ((unsigned)d < (unsigned)N && (unsigned)s < (unsigned)N) {
            int pos = atomicAdd(&cursor[d], 1);
            csr_src[pos] = s;
        }
    }
}

// ---------------- prep0: Bt3, BtF (=W1@W2 folded), bias12, proj1, proj3 ----------------
__global__ void prep0_kernel(const float* __restrict__ W1, const float* __restrict__ W2,
                             const float* __restrict__ W3, const float* __restrict__ b1,
                             const float* __restrict__ a1s, const float* __restrict__ a1d,
                             const float* __restrict__ a3s, const float* __restrict__ a3d,
                             __hip_bfloat16* __restrict__ Bt3, __hip_bfloat16* __restrict__ BtF,
                             float* __restrict__ bias12,
                             float* __restrict__ ps1, float* __restrict__ pd1,
                             float* __restrict__ ps3, float* __restrict__ pd3) {
    int b = blockIdx.x, t = threadIdx.x;
    if (b < 128) {  // Bt3 [64][512]
        int idx = b * 256 + t;
        int c = idx >> 9, r = idx & 511;
        int h = r >> 7, kk = r & 127;
        st1(&Bt3[idx], W3[(size_t)kk * 256 + h * 64 + c] * 0.25f);
        return;
    }
    b -= 128;
    if (b < 128) {  // BtF [128][256]
        int idx = b * 256 + t;
        int m = idx >> 8, k = idx & 255;
        int h = k >> 6, kin = k & 63;
        float acc = 0.f;
        for (int c = 0; c < 64; ++c)
            acc += W1[(size_t)kin * 256 + h * 64 + c] * W2[(size_t)(h * 64 + c) * 128 + m];
        st1(&BtF[idx], acc);
        return;
    }
    b -= 128;
    if (b < 1) {  // bias12
        if (t < 128) {
            float acc = 0.f;
            for (int j = 0; j < 256; ++j) acc += b1[j] * W2[(size_t)j * 128 + t];
            bias12[t] = acc;
        }
        return;
    }
    b -= 1;
    if (b < 1) {  // proj1
        int h = t >> 6, k = t & 63;
        float ss = 0.f, sd = 0.f;
        for (int c = 0; c < 64; ++c) {
            float w = W1[(size_t)k * 256 + h * 64 + c];
            ss += w * a1s[h * 64 + c];
            sd += w * a1d[h * 64 + c];
        }
        ps1[t] = ss;
        pd1[t] = sd;
        return;
    }
    b -= 1;
    if (b < 2) {  // proj3
        int idx = b * 256 + t;
        int h = idx >> 7, k = idx & 127;
        float ss = 0.f, sd = 0.f;
        for (int c = 0; c < 64; ++c) {
            float w = W3[(size_t)k * 256 + h * 64 + c];
            ss += w * a3s[h * 64 + c];
            sd += w * a3d[h * 64 + c];
        }
        ps3[idx] = ss;
        pd3[idx] = sd;
        return;
    }
}

// ---------------- x -> bf16 conversion + fused L1 logits ----------------
__global__ void xconv_alx_kernel(const float* __restrict__ x, const float* __restrict__ ps1,
                                 const float* __restrict__ pd1, __hip_bfloat16* __restrict__ xb,
                                 float* __restrict__ als, float* __restrict__ ald, int n8) {
    int i = blockIdx.x * blockDim.x + threadIdx.x;
    if (i >= n8) return;
    int r = i >> 3, sub = i & 7;
    int cbase = sub * 8;
    float4 a = *reinterpret_cast<const float4*>(&x[(size_t)i * 8]);
    float4 c = *reinterpret_cast<const float4*>(&x[(size_t)i * 8 + 4]);
    st4(&xb[(size_t)i * 8], a);
    st4(&xb[(size_t)i * 8 + 4], c);
    float ss[4], sd[4];
#pragma unroll
    for (int h = 0; h < 4; ++h) {
        float4 s0 = *reinterpret_cast<const float4*>(&ps1[h * 64 + cbase]);
        float4 s1 = *reinterpret_cast<const float4*>(&ps1[h * 64 + cbase + 4]);
        float4 d0 = *reinterpret_cast<const float4*>(&pd1[h * 64 + cbase]);
        float4 d1 = *reinterpret_cast<const float4*>(&pd1[h * 64 + cbase + 4]);
        ss[h] = a.x * s0.x + a.y * s0.y + a.z * s0.z + a.w * s0.w
              + c.x * s1.x + c.y * s1.y + c.z * s1.z + c.w * s1.w;
        sd[h] = a.x * d0.x + a.y * d0.y + a.z * d0.z + a.w * d0.w
              + c.x * d1.x + c.y * d1.y + c.z * d1.z + c.w * d1.w;
    }
#pragma unroll
    for (int off = 1; off < 8; off <<= 1) {
#pragma unroll
        for (int h = 0; h < 4; ++h) {
            ss[h] += __shfl_xor(ss[h], off);
            sd[h] += __shfl_xor(sd[h], off);
        }
    }
    if (sub == 0) {
        *reinterpret_cast<float4*>(&als[(size_t)r * 4]) = make_float4(ss[0], ss[1], ss[2], ss[3]);
        *reinterpret_cast<float4*>(&ald[(size_t)r * 4]) = make_float4(sd[0], sd[1], sd[2], sd[3]);
    }
}

// ---------------- fused gather (pre-agg): shuffle weights, 1 wave per block ----------------
template <int K, typename TIN, typename TOUT>
__global__ __launch_bounds__(64) void gather_pre_kernel(
    const TIN* __restrict__ x, const float* __restrict__ als,
    const float* __restrict__ ald, const int* __restrict__ rowptr,
    const int* __restrict__ csr, TOUT* __restrict__ agg, int N) {
    constexpr int V = K / 64;  // 1 (K=64) or 2 (K=128)
    int wave = blockIdx.x;
    int lane = threadIdx.x;
    if (wave >= N) return;
    int h4 = lane & 3, e4 = lane >> 2;
    float aldv = ald[wave * 4 + h4];
    float s0 = 0.f, s1 = 0.f, s2 = 0.f, s3 = 0.f;
    float acc[4][V] = {};
    int beg = rowptr[wave], end = rowptr[wave + 1];
    for (int kc = beg; kc < end; kc += 16) {
        int cnt = end - kc;
        if (cnt > 16) cnt = 16;
        int j = kc + e4;
        int src = csr[(j < end) ? j : beg];
        float e = als[src * 4 + h4] + aldv;
        e = fmaxf(e, 0.2f * e);
        float myw = __expf(e);
        if (cnt == 16) {
            int sj[16];
#pragma unroll
            for (int jj = 0; jj < 16; ++jj) sj[jj] = __shfl(src, jj * 4);
            if (V == 1) {
                float pv[16];
#pragma unroll
                for (int jj = 0; jj < 16; ++jj) pv[jj] = ld1(&x[(size_t)sj[jj] * K + lane]);
#pragma unroll
                for (int jj = 0; jj < 16; ++jj) {
                    float w0 = __shfl(myw, jj * 4 + 0), w1 = __shfl(myw, jj * 4 + 1);
                    float w2 = __shfl(myw, jj * 4 + 2), w3 = __shfl(myw, jj * 4 + 3);
                    s0 += w0; s1 += w1; s2 += w2; s3 += w3;
                    acc[0][0] += w0 * pv[jj]; acc[1][0] += w1 * pv[jj];
                    acc[2][0] += w2 * pv[jj]; acc[3][0] += w3 * pv[jj];
                }
            } else {
                float2 pv[16];
#pragma unroll
                for (int jj = 0; jj < 16; ++jj) pv[jj] = ld2(&x[(size_t)sj[jj] * K + lane * 2]);
#pragma unroll
                for (int jj = 0; jj < 16; ++jj) {
                    float w0 = __shfl(myw, jj * 4 + 0), w1 = __shfl(myw, jj * 4 + 1);
                    float w2 = __shfl(myw, jj * 4 + 2), w3 = __shfl(myw, jj * 4 + 3);
                    s0 += w0; s1 += w1; s2 += w2; s3 += w3;
                    acc[0][0] += w0 * pv[jj].x; acc[0][1] += w0 * pv[jj].y;
                    acc[1][0] += w1 * pv[jj].x; acc[1][1] += w1 * pv[jj].y;
                    acc[2][0] += w2 * pv[jj].x; acc[2][1] += w2 * pv[jj].y;
                    acc[3][0] += w3 * pv[jj].x; acc[3][1] += w3 * pv[jj].y;
                }
            }
        } else {
            for (int jj = 0; jj < cnt; ++jj) {
                int sjj = __shfl(src, jj * 4);
                float w0 = __shfl(myw, jj * 4 + 0), w1 = __shfl(myw, jj * 4 + 1);
                float w2 = __shfl(myw, jj * 4 + 2), w3 = __shfl(myw, jj * 4 + 3);
                s0 += w0; s1 += w1; s2 += w2; s3 += w3;
                if (V == 1) {
                    float v = ld1(&x[(size_t)sjj * K + lane]);
                    acc[0][0] += w0 * v; acc[1][0] += w1 * v;
                    acc[2][0] += w2 * v; acc[3][0] += w3 * v;
                } else {
                    float2 v = ld2(&x[(size_t)sjj * K + lane * 2]);
                    acc[0][0] += w0 * v.x; acc[0][1] += w0 * v.y;
                    acc[1][0] += w1 * v.x; acc[1][1] += w1 * v.y;
                    acc[2][0] += w2 * v.x; acc[2][1] += w2 * v.y;
                    acc[3][0] += w3 * v.x; acc[3][1] += w3 * v.y;
                }
            }
        }
    }
    float inv[4] = {1.f / (s0 + 1e-16f), 1.f / (s1 + 1e-16f),
                    1.f / (s2 + 1e-16f), 1.f / (s3 + 1e-16f)};
    size_t o = (size_t)wave * 4 * K;
#pragma unroll
    for (int h = 0; h < 4; ++h) {
        if (V == 1) {
            st1(&agg[o + h * K + lane], acc[h][0] * inv[h]);
        } else {
            st2(&agg[o + h * K + lane * 2], acc[h][0] * inv[h], acc[h][1] * inv[h]);
        }
    }
}

// ---------------- fused gather (post-GEMM L2) + L3 logits: shuffle weights, 1 wave per block ----------------
template <typename TIN, typename TOUT>
__global__ __launch_bounds__(64) void gather_post32_alx_kernel(
    const TIN* __restrict__ h2, const float* __restrict__ als,
    const float* __restrict__ ald, const int* __restrict__ rowptr,
    const int* __restrict__ csr, const float* __restrict__ bias,
    const float* __restrict__ ps3, const float* __restrict__ pd3,
    TOUT* __restrict__ outp,
    float* __restrict__ als3, float* __restrict__ ald3, int N) {
    int wave = blockIdx.x;
    int lane = threadIdx.x;
    if (wave >= N) return;
    int h4 = lane & 3, e4 = lane >> 2;
    int hh = lane >> 4, l16 = lane & 15;
    float aldv = ald[wave * 4 + h4];
    float s = 0.f, a0 = 0.f, a1 = 0.f;
    int beg = rowptr[wave], end = rowptr[wave + 1];
    for (int kc = beg; kc < end; kc += 16) {
        int cnt = end - kc;
        if (cnt > 16) cnt = 16;
        int j = kc + e4;
        int src = csr[(j < end) ? j : beg];
        float e = als[src * 4 + h4] + aldv;
        e = fmaxf(e, 0.2f * e);
        float myw = __expf(e);
        if (cnt == 16) {
            int sj[16];
#pragma unroll
            for (int jj = 0; jj < 16; ++jj) sj[jj] = __shfl(src, jj * 4);
            float2 pv[16];
#pragma unroll
            for (int jj = 0; jj < 16; ++jj)
                pv[jj] = ld2(&h2[(size_t)sj[jj] * 128 + hh * 32 + l16 * 2]);
#pragma unroll
            for (int jj = 0; jj < 16; ++jj) {
                float w = __shfl(myw, jj * 4 + hh);
                s += w;
                a0 += w * pv[jj].x;
                a1 += w * pv[jj].y;
            }
        } else {
            for (int jj = 0; jj < cnt; ++jj) {
                int sjj = __shfl(src, jj * 4);
                float w = __shfl(myw, jj * 4 + hh);
                s += w;
                float2 v = ld2(&h2[(size_t)sjj * 128 + hh * 32 + l16 * 2]);
                a0 += w * v.x;
                a1 += w * v.y;
            }
        }
    }
    float inv = 1.f / (s + 1e-16f);
    int c = hh * 32 + l16 * 2;
    float v0 = a0 * inv + bias[c];
    float v1 = a1 * inv + bias[c + 1];
    st2(&outp[(size_t)wave * 128 + c], v0, v1);

    // ---- layer-3 logits in-register ----
    float sArr[4], dArr[4];
#pragma unroll
    for (int h = 0; h < 4; ++h) {
        float2 vs = *reinterpret_cast<const float2*>(&ps3[h * 128 + c]);
        float2 vd = *reinterpret_cast<const float2*>(&pd3[h * 128 + c]);
        sArr[h] = v0 * vs.x + v1 * vs.y;
        dArr[h] = v0 * vd.x + v1 * vd.y;
    }
#pragma unroll
    for (int off = 1; off < 64; off <<= 1) {
#pragma unroll
        for (int h = 0; h < 4; ++h) {
            sArr[h] += __shfl_xor(sArr[h], off);
            dArr[h] += __shfl_xor(dArr[h], off);
        }
    }
    if (lane < 4) {
        float os = (lane == 0) ? sArr[0] : (lane == 1) ? sArr[1] : (lane == 2) ? sArr[2] : sArr[3];
        float od = (lane == 0) ? dArr[0] : (lane == 1) ? dArr[1] : (lane == 2) ? dArr[2] : dArr[3];
        als3[wave * 4 + lane] = os;
        ald3[wave * 4 + lane] = od;
    }
}

// ---------------- MFMA GEMM (BM=128 BN=64 BK=32), optional fused col-dot logits ----------------
template <typename TOUT>
__global__ __launch_bounds__(256) void mfma_gemm_kernel(
    const __hip_bfloat16* __restrict__ A, int lda, int aSel,
    const __hip_bfloat16* __restrict__ Bt,
    TOUT* __restrict__ O, int ldo,
    const float* __restrict__ bias,
    const float* __restrict__ a2s, const float* __restrict__ a2d,
    float* __restrict__ oals, float* __restrict__ oald,
    int N, int K) {
    __shared__ __hip_bfloat16 As[128][40];
    __shared__ __hip_bfloat16 Bs[64][40];
    int col0 = blockIdx.x * 64;
    int row0 = blockIdx.y * 128;
    int aOff = aSel ? col0 : 0;
    int tid = threadIdx.x;
    int wv = tid >> 6, lane = tid & 63;
    int g = lane >> 4, l16 = lane & 15;
    f32x4 acc[2][4] = {};

    for (int k0 = 0; k0 < K; k0 += 32) {
#pragma unroll
        for (int i = 0; i < 2; ++i) {
            int idx = tid + i * 256;
            int r = idx >> 2, h4 = idx & 3;
            int gr = row0 + r;
            uint4 v = make_uint4(0, 0, 0, 0);
            if (gr < N) v = *reinterpret_cast<const uint4*>(&A[(size_t)gr * lda + aOff + k0 + h4 * 8]);
            *reinterpret_cast<uint4*>(&As[r][h4 * 8]) = v;
        }
        {
            int r = tid >> 2, h4 = tid & 3;
            uint4 v = *reinterpret_cast<const uint4*>(&Bt[(size_t)(col0 + r) * K + k0 + h4 * 8]);
            *reinterpret_cast<uint4*>(&Bs[r][h4 * 8]) = v;
        }
        __syncthreads();
        s16x8 af[2], bf[4];
#pragma unroll
        for (int m = 0; m < 2; ++m)
            af[m] = *reinterpret_cast<const s16x8*>(&As[wv * 32 + m * 16 + l16][g * 8]);
#pragma unroll
        for (int n = 0; n < 4; ++n)
            bf[n] = *reinterpret_cast<const s16x8*>(&Bs[n * 16 + l16][g * 8]);
#pragma unroll
        for (int m = 0; m < 2; ++m)
#pragma unroll
            for (int n = 0; n < 4; ++n)
                acc[m][n] = __builtin_amdgcn_mfma_f32_16x16x32_bf16(af[m], bf[n], acc[m][n], 0, 0, 0);
        __syncthreads();
    }
#pragma unroll
    for (int m = 0; m < 2; ++m) {
#pragma unroll
        for (int rr = 0; rr < 4; ++rr) {
            int row = row0 + wv * 32 + m * 16 + g * 4 + rr;
            float vv[4];
#pragma unroll
            for (int n = 0; n < 4; ++n) {
                vv[n] = acc[m][n][rr];
                if (bias) vv[n] += bias[col0 + n * 16 + l16];
            }
            if (row < N) {
#pragma unroll
                for (int n = 0; n < 4; ++n)
                    st1(&O[(size_t)row * ldo + col0 + n * 16 + l16], vv[n]);
            }
            if (oals) {
                float ts0 = vv[0] * a2s[col0 + l16]      + vv[1] * a2s[col0 + 16 + l16];
                float ts1 = vv[2] * a2s[col0 + 32 + l16] + vv[3] * a2s[col0 + 48 + l16];
                float td0 = vv[0] * a2d[col0 + l16]      + vv[1] * a2d[col0 + 16 + l16];
                float td1 = vv[2] * a2d[col0 + 32 + l16] + vv[3] * a2d[col0 + 48 + l16];
#pragma unroll
                for (int off = 1; off < 16; off <<= 1) {
                    ts0 += __shfl_xor(ts0, off); ts1 += __shfl_xor(ts1, off);
                    td0 += __shfl_xor(td0, off); td1 += __shfl_xor(td1, off);
                }
                if (l16 == 0 && row < N) {
                    int hb = col0 >> 5;  // heads 2x, 2x+1
                    oals[(size_t)row * 4 + hb]     = ts0;
                    oals[(size_t)row * 4 + hb + 1] = ts1;
                    oald[(size_t)row * 4 + hb]     = td0;
                    oald[(size_t)row * 4 + hb + 1] = td1;
                }
            }
        }
    }
}

// ---------------- launch ----------------
extern "C" void kernel_launch(void* const* d_in, const int* in_sizes, int n_in,
                              void* d_out, int out_size, void* d_ws, size_t ws_size,
                              hipStream_t stream) {
    const float* x      = (const float*)d_in[0];
    const int*   eidx   = (const int*)d_in[1];
    const float* W1     = (const float*)d_in[2];
    const float* a1_src = (const float*)d_in[3];
    const float* a1_dst = (const float*)d_in[4];
    const float* b1     = (const float*)d_in[5];
    const float* W2     = (const float*)d_in[6];
    const float* a2_src = (const float*)d_in[7];
    const float* a2_dst = (const float*)d_in[8];
    const float* b2     = (const float*)d_in[9];
    const float* W3     = (const float*)d_in[10];
    const float* a3_src = (const float*)d_in[11];
    const float* a3_dst = (const float*)d_in[12];
    const float* b3     = (const float*)d_in[13];
    float* out = (float*)d_out;

    const int N = in_sizes[0] / 64;      // 50000
    const int E = in_sizes[1] / 2;       // 800000
    const int NB = (N + 1023) / 1024;

    // ---- workspace ----
    int* rowptr = (int*)d_ws;
    int* deg    = rowptr + (N + 1);
    int* cursor = deg + N;
    int* csr    = cursor + N;
    int* bsum   = csr + E;
    int* boff   = bsum + NB;
    uintptr_t pa = (uintptr_t)(boff + NB);
    pa = (pa + 255) & ~(uintptr_t)255;
    float* als  = (float*)pa;                       // N*4
    float* ald  = als + (size_t)N * 4;              // N*4
    float* als3 = ald + (size_t)N * 4;              // N*4
    float* ald3 = als3 + (size_t)N * 4;             // N*4
    float* ps1  = ald3 + (size_t)N * 4;             // 256
    float* pd1  = ps1 + 256;                        // 256
    float* ps3  = pd1 + 256;                        // 512
    float* pd3  = ps3 + 512;                        // 512
    float* bias12 = pd3 + 512;                      // 128
    __hip_bfloat16* Bt3 = (__hip_bfloat16*)(bias12 + 128);  // 64*512
    __hip_bfloat16* BtF = Bt3 + 64 * 512;                   // 128*256
    uintptr_t pf = (uintptr_t)(BtF + 128 * 256);
    pf = (pf + 255) & ~(uintptr_t)255;
    float* F    = (float*)pf;

    // arena (float units): xb 32N | agg1b 128N | h2b 64N | out2b 64N | agg3 256N = 544N
    __hip_bfloat16* xb    = (__hip_bfloat16*)F;
    __hip_bfloat16* agg1b = (__hip_bfloat16*)(F + (size_t)N * 32);
    __hip_bfloat16* h2b   = (__hip_bfloat16*)(F + (size_t)N * 160);
    __hip_bfloat16* out2b = (__hip_bfloat16*)(F + (size_t)N * 224);
    __hip_bfloat16* agg3  = (__hip_bfloat16*)(F + (size_t)N * 288);

    // ---- CSR build ----
    hipMemsetAsync(deg, 0, (size_t)N * sizeof(int), stream);
    deg_kernel<<<(E + 255) / 256, 256, 0, stream>>>(eidx, deg, E, N);
    reduce_kernel<<<NB, 256, 0, stream>>>(deg, bsum, N);
    scan_bsum_kernel<<<1, 64, 0, stream>>>(bsum, boff, NB, rowptr + N);
    block_scan_kernel<<<NB, 256, 0, stream>>>(deg, boff, rowptr, cursor, N);
    scatter_kernel<<<(E + 255) / 256, 256, 0, stream>>>(eidx, cursor, csr, E, N);

    // ---- prep0 (weights/proj) then x-conv + fused L1 logits ----
    prep0_kernel<<<128 + 128 + 1 + 1 + 2, 256, 0, stream>>>(
        W1, W2, W3, b1, a1_src, a1_dst, a3_src, a3_dst,
        Bt3, BtF, bias12, ps1, pd1, ps3, pd3);
    const int n8 = N * 8;
    xconv_alx_kernel<<<(n8 + 255) / 256, 256, 0, stream>>>(x, ps1, pd1, xb, als, ald, n8);

    const int rowB128 = (N + 127) / 128;

    // ---- layer 1 gather + fused L1L2-GEMM (with fused L2 logits) ----
    gather_pre_kernel<64, __hip_bfloat16, __hip_bfloat16><<<N, 64, 0, stream>>>(
        xb, als, ald, rowptr, csr, agg1b, N);
    mfma_gemm_kernel<__hip_bfloat16><<<dim3(2, rowB128), 256, 0, stream>>>(
        agg1b, 256, 0, BtF, h2b, 128, bias12, a2_src, a2_dst, als, ald, N, 256);

    // ---- layer 2: gather (fused layer-3 logits) ----
    gather_post32_alx_kernel<__hip_bfloat16, __hip_bfloat16><<<N, 64, 0, stream>>>(
        h2b, als, ald, rowptr, csr, b2, ps3, pd3, out2b, als3, ald3, N);

    // ---- layer 3: gather + stacked GEMM (mean folded) ----
    gather_pre_kernel<128, __hip_bfloat16, __hip_bfloat16><<<N, 64, 0, stream>>>(
        out2b, als3, ald3, rowptr, csr, agg3, N);
    mfma_gemm_kernel<float><<<dim3(1, rowB128), 256, 0, stream>>>(
        agg3, 512, 0, Bt3, out, 64, b3, nullptr, nullptr, nullptr, nullptr, N, 512);
}

// Round 18
// 312.467 us; speedup vs baseline: 1.0603x; 1.0245x over previous
//
#include <hip/hip_runtime.h>
#include <hip/hip_bf16.h>

#define HEADS 4

typedef __attribute__((ext_vector_type(4))) float f32x4;
typedef __attribute__((ext_vector_type(2))) float f32x2;
typedef __attribute__((ext_vector_type(8))) short s16x8;

// ---------------- bf16 helpers ----------------
__device__ __forceinline__ float u2f(unsigned short u) {
    return __uint_as_float(((unsigned)u) << 16);
}
__device__ __forceinline__ unsigned short rne(float v) {
    unsigned b = __float_as_uint(v);
    return (unsigned short)((b + 0x7FFF + ((b >> 16) & 1)) >> 16);
}
__device__ __forceinline__ float ld1(const float* p) { return *p; }
__device__ __forceinline__ float ld1(const __hip_bfloat16* p) {
    return u2f(*reinterpret_cast<const unsigned short*>(p));
}
__device__ __forceinline__ float2 ld2(const float* p) { return *reinterpret_cast<const float2*>(p); }
__device__ __forceinline__ float2 ld2(const __hip_bfloat16* p) {
    ushort2 u = *reinterpret_cast<const ushort2*>(p);
    return make_float2(u2f(u.x), u2f(u.y));
}
__device__ __forceinline__ float4 ld4(const float* p) { return *reinterpret_cast<const float4*>(p); }
__device__ __forceinline__ float4 ld4(const __hip_bfloat16* p) {
    ushort4 u = *reinterpret_cast<const ushort4*>(p);
    return make_float4(u2f(u.x), u2f(u.y), u2f(u.z), u2f(u.w));
}
__device__ __forceinline__ void st1(float* p, float v) { *p = v; }
__device__ __forceinline__ void st1(__hip_bfloat16* p, float v) {
    *reinterpret_cast<unsigned short*>(p) = rne(v);
}
__device__ __forceinline__ void st2(float* p, float a, float b) {
    *reinterpret_cast<float2*>(p) = make_float2(a, b);
}
__device__ __forceinline__ void st2(__hip_bfloat16* p, float a, float b) {
    *reinterpret_cast<ushort2*>(p) = make_ushort2(rne(a), rne(b));
}
__device__ __forceinline__ void st4(float* p, float4 v) { *reinterpret_cast<float4*>(p) = v; }
__device__ __forceinline__ void st4(__hip_bfloat16* p, float4 v) {
    *reinterpret_cast<ushort4*>(p) = make_ushort4(rne(v.x), rne(v.y), rne(v.z), rne(v.w));
}

// ---------------- inline int64-layout detection ----------------
__device__ __forceinline__ int detect64(const int* __restrict__ e) {
    return ((e[1] | e[3] | e[5] | e[7]) == 0) ? 1 : 0;
}
__device__ __forceinline__ int edge_elem(const int* e, size_t idx, int is64) {
    return is64 ? e[2 * idx] : e[idx];
}

// ---------------- CSR build ----------------
__global__ void deg_kernel(const int* __restrict__ eidx, int* __restrict__ deg, int E, int N) {
    int e = blockIdx.x * blockDim.x + threadIdx.x;
    if (e < E) {
        int is64 = detect64(eidx);
        int d = edge_elem(eidx, (size_t)E + e, is64);
        if ((unsigned)d < (unsigned)N) atomicAdd(&deg[d], 1);
    }
}

__global__ void reduce_kernel(const int* __restrict__ deg, int* __restrict__ bsum, int n) {
    __shared__ int sdata[256];
    int base = blockIdx.x * 1024;
    int t = threadIdx.x;
    int v = 0;
#pragma unroll
    for (int j = 0; j < 4; ++j) {
        int i = base + t + j * 256;
        if (i < n) v += deg[i];
    }
    sdata[t] = v;
    __syncthreads();
    for (int off = 128; off > 0; off >>= 1) {
        if (t < off) sdata[t] += sdata[t + off];
        __syncthreads();
    }
    if (t == 0) bsum[blockIdx.x] = sdata[0];
}

__global__ void scan_bsum_kernel(const int* __restrict__ bsum, int* __restrict__ boff,
                                 int nb, int* __restrict__ totalp) {
    int lane = threadIdx.x;
    int carry = 0;
    for (int base = 0; base < nb; base += 64) {
        int i = base + lane;
        int v = (i < nb) ? bsum[i] : 0;
        int inc = v;
        for (int off = 1; off < 64; off <<= 1) {
            int tt = __shfl_up(inc, off);
            if (lane >= off) inc += tt;
        }
        if (i < nb) boff[i] = carry + inc - v;
        carry += __shfl(inc, 63);
    }
    if (lane == 0) *totalp = carry;
}

__global__ void block_scan_kernel(const int* __restrict__ deg, const int* __restrict__ boff,
                                  int* __restrict__ rowptr, int* __restrict__ cursor, int n) {
    __shared__ int wsum[4];
    int base = blockIdx.x * 1024;
    int t = threadIdx.x;
    int lane = t & 63, w = t >> 6;
    int v[4];
    int lsum = 0;
#pragma unroll
    for (int j = 0; j < 4; ++j) {
        int i = base + t * 4 + j;
        v[j] = (i < n) ? deg[i] : 0;
        lsum += v[j];
    }
    int inc = lsum;
    for (int off = 1; off < 64; off <<= 1) {
        int tt = __shfl_up(inc, off);
        if (lane >= off) inc += tt;
    }
    if (lane == 63) wsum[w] = inc;
    __syncthreads();
    int woff = 0;
    for (int i = 0; i < w; ++i) woff += wsum[i];
    int ex = boff[blockIdx.x] + woff + inc - lsum;
#pragma unroll
    for (int j = 0; j < 4; ++j) {
        int i = base + t * 4 + j;
        if (i < n) { rowptr[i] = ex; cursor[i] = ex; }
        ex += v[j];
    }
}

__global__ void scatter_kernel(const int* __restrict__ eidx, int* __restrict__ cursor,
                               int* __restrict__ csr_src, int E, int N) {
    int e = blockIdx.x * blockDim.x + threadIdx.x;
    if (e < E) {
        int is64 = detect64(eidx);
        int s = edge_elem(eidx, (size_t)e, is64);
        int d = edge_elem(eidx, (size_t)E + e, is64);
        if ((unsigned)d < (unsigned)N && (unsigned)s < (unsigned)N) {
            int pos = atomicAdd(&cursor[d], 1);
            csr_src[pos] = s;
        }
    }
}

// ---------------- prep0: Bt3, BtF (=W1@W2 folded), bias12, proj1, proj3 ----------------
__global__ void prep0_kernel(const float* __restrict__ W1, const float* __restrict__ W2,
                             const float* __restrict__ W3, const float* __restrict__ b1,
                             const float* __restrict__ a1s, const float* __restrict__ a1d,
                             const float* __restrict__ a3s, const float* __restrict__ a3d,
                             __hip_bfloat16* __restrict__ Bt3, __hip_bfloat16* __restrict__ BtF,
                             float* __restrict__ bias12,
                             float* __restrict__ ps1, float* __restrict__ pd1,
                             float* __restrict__ ps3, float* __restrict__ pd3) {
    int b = blockIdx.x, t = threadIdx.x;
    if (b < 128) {  // Bt3 [64][512]
        int idx = b * 256 + t;
        int c = idx >> 9, r = idx & 511;
        int h = r >> 7, kk = r & 127;
        st1(&Bt3[idx], W3[(size_t)kk * 256 + h * 64 + c] * 0.25f);
        return;
    }
    b -= 128;
    if (b < 128) {  // BtF [128][256]
        int idx = b * 256 + t;
        int m = idx >> 8, k = idx & 255;
        int h = k >> 6, kin = k & 63;
        float acc = 0.f;
        for (int c = 0; c < 64; ++c)
            acc += W1[(size_t)kin * 256 + h * 64 + c] * W2[(size_t)(h * 64 + c) * 128 + m];
        st1(&BtF[idx], acc);
        return;
    }
    b -= 128;
    if (b < 1) {  // bias12
        if (t < 128) {
            float acc = 0.f;
            for (int j = 0; j < 256; ++j) acc += b1[j] * W2[(size_t)j * 128 + t];
            bias12[t] = acc;
        }
        return;
    }
    b -= 1;
    if (b < 1) {  // proj1
        int h = t >> 6, k = t & 63;
        float ss = 0.f, sd = 0.f;
        for (int c = 0; c < 64; ++c) {
            float w = W1[(size_t)k * 256 + h * 64 + c];
            ss += w * a1s[h * 64 + c];
            sd += w * a1d[h * 64 + c];
        }
        ps1[t] = ss;
        pd1[t] = sd;
        return;
    }
    b -= 1;
    if (b < 2) {  // proj3
        int idx = b * 256 + t;
        int h = idx >> 7, k = idx & 127;
        float ss = 0.f, sd = 0.f;
        for (int c = 0; c < 64; ++c) {
            float w = W3[(size_t)k * 256 + h * 64 + c];
            ss += w * a3s[h * 64 + c];
            sd += w * a3d[h * 64 + c];
        }
        ps3[idx] = ss;
        pd3[idx] = sd;
        return;
    }
}

// ---------------- x -> bf16 conversion + fused L1 logits ----------------
__global__ void xconv_alx_kernel(const float* __restrict__ x, const float* __restrict__ ps1,
                                 const float* __restrict__ pd1, __hip_bfloat16* __restrict__ xb,
                                 float* __restrict__ als, float* __restrict__ ald, int n8) {
    int i = blockIdx.x * blockDim.x + threadIdx.x;
    if (i >= n8) return;
    int r = i >> 3, sub = i & 7;
    int cbase = sub * 8;
    float4 a = *reinterpret_cast<const float4*>(&x[(size_t)i * 8]);
    float4 c = *reinterpret_cast<const float4*>(&x[(size_t)i * 8 + 4]);
    st4(&xb[(size_t)i * 8], a);
    st4(&xb[(size_t)i * 8 + 4], c);
    float ss[4], sd[4];
#pragma unroll
    for (int h = 0; h < 4; ++h) {
        float4 s0 = *reinterpret_cast<const float4*>(&ps1[h * 64 + cbase]);
        float4 s1 = *reinterpret_cast<const float4*>(&ps1[h * 64 + cbase + 4]);
        float4 d0 = *reinterpret_cast<const float4*>(&pd1[h * 64 + cbase]);
        float4 d1 = *reinterpret_cast<const float4*>(&pd1[h * 64 + cbase + 4]);
        ss[h] = a.x * s0.x + a.y * s0.y + a.z * s0.z + a.w * s0.w
              + c.x * s1.x + c.y * s1.y + c.z * s1.z + c.w * s1.w;
        sd[h] = a.x * d0.x + a.y * d0.y + a.z * d0.z + a.w * d0.w
              + c.x * d1.x + c.y * d1.y + c.z * d1.z + c.w * d1.w;
    }
#pragma unroll
    for (int off = 1; off < 8; off <<= 1) {
#pragma unroll
        for (int h = 0; h < 4; ++h) {
            ss[h] += __shfl_xor(ss[h], off);
            sd[h] += __shfl_xor(sd[h], off);
        }
    }
    if (sub == 0) {
        *reinterpret_cast<float4*>(&als[(size_t)r * 4]) = make_float4(ss[0], ss[1], ss[2], ss[3]);
        *reinterpret_cast<float4*>(&ald[(size_t)r * 4]) = make_float4(sd[0], sd[1], sd[2], sd[3]);
    }
}

// ---------------- fused gather (pre-agg): shuffle weights, 1 wave/block, packed-f32 math ----------------
template <int K, typename TIN, typename TOUT>
__global__ __launch_bounds__(64) void gather_pre_kernel(
    const TIN* __restrict__ x, const float* __restrict__ als,
    const float* __restrict__ ald, const int* __restrict__ rowptr,
    const int* __restrict__ csr, TOUT* __restrict__ agg, int N) {
    constexpr int V = K / 64;  // 1 (K=64) or 2 (K=128)
    int wave = blockIdx.x;
    int lane = threadIdx.x;
    if (wave >= N) return;
    int h4 = lane & 3, e4 = lane >> 2;
    float aldv = ald[wave * 4 + h4];
    f32x2 s01 = {0.f, 0.f}, s23 = {0.f, 0.f};
    // V==1: acc[0]=heads(0,1), acc[1]=heads(2,3) of the lane's single channel.
    // V==2: acc[h] = 2 channels of head h.
    f32x2 acc[V == 1 ? 2 : 4] = {};
    int beg = rowptr[wave], end = rowptr[wave + 1];
    for (int kc = beg; kc < end; kc += 16) {
        int cnt = end - kc;
        if (cnt > 16) cnt = 16;
        int j = kc + e4;
        int src = csr[(j < end) ? j : beg];
        float e = als[src * 4 + h4] + aldv;
        e = fmaxf(e, 0.2f * e);
        float myw = __expf(e);
        if (cnt == 16) {
            int sj[16];
#pragma unroll
            for (int jj = 0; jj < 16; ++jj) sj[jj] = __shfl(src, jj * 4);
            if (V == 1) {
                float pv[16];
#pragma unroll
                for (int jj = 0; jj < 16; ++jj) pv[jj] = ld1(&x[(size_t)sj[jj] * K + lane]);
#pragma unroll
                for (int jj = 0; jj < 16; ++jj) {
                    f32x2 w01 = {__shfl(myw, jj * 4 + 0), __shfl(myw, jj * 4 + 1)};
                    f32x2 w23 = {__shfl(myw, jj * 4 + 2), __shfl(myw, jj * 4 + 3)};
                    s01 += w01; s23 += w23;
                    acc[0] += w01 * pv[jj];
                    acc[1] += w23 * pv[jj];
                }
            } else {
                float2 pv[16];
#pragma unroll
                for (int jj = 0; jj < 16; ++jj) pv[jj] = ld2(&x[(size_t)sj[jj] * K + lane * 2]);
#pragma unroll
                for (int jj = 0; jj < 16; ++jj) {
                    float w0 = __shfl(myw, jj * 4 + 0), w1 = __shfl(myw, jj * 4 + 1);
                    float w2 = __shfl(myw, jj * 4 + 2), w3 = __shfl(myw, jj * 4 + 3);
                    f32x2 pvv = {pv[jj].x, pv[jj].y};
                    s01 += (f32x2){w0, w1}; s23 += (f32x2){w2, w3};
                    acc[0] += w0 * pvv; acc[1] += w1 * pvv;
                    acc[2] += w2 * pvv; acc[3] += w3 * pvv;
                }
            }
        } else {
            for (int jj = 0; jj < cnt; ++jj) {
                int sjj = __shfl(src, jj * 4);
                float w0 = __shfl(myw, jj * 4 + 0), w1 = __shfl(myw, jj * 4 + 1);
                float w2 = __shfl(myw, jj * 4 + 2), w3 = __shfl(myw, jj * 4 + 3);
                f32x2 w01 = {w0, w1}, w23 = {w2, w3};
                s01 += w01; s23 += w23;
                if (V == 1) {
                    float v = ld1(&x[(size_t)sjj * K + lane]);
                    acc[0] += w01 * v;
                    acc[1] += w23 * v;
                } else {
                    float2 v = ld2(&x[(size_t)sjj * K + lane * 2]);
                    f32x2 pvv = {v.x, v.y};
                    acc[0] += w0 * pvv; acc[1] += w1 * pvv;
                    acc[2] += w2 * pvv; acc[3] += w3 * pvv;
                }
            }
        }
    }
    float inv[4] = {1.f / (s01.x + 1e-16f), 1.f / (s01.y + 1e-16f),
                    1.f / (s23.x + 1e-16f), 1.f / (s23.y + 1e-16f)};
    size_t o = (size_t)wave * 4 * K;
    if (V == 1) {
        st1(&agg[o + 0 * K + lane], acc[0].x * inv[0]);
        st1(&agg[o + 1 * K + lane], acc[0].y * inv[1]);
        st1(&agg[o + 2 * K + lane], acc[1].x * inv[2]);
        st1(&agg[o + 3 * K + lane], acc[1].y * inv[3]);
    } else {
#pragma unroll
        for (int h = 0; h < 4; ++h)
            st2(&agg[o + h * K + lane * 2], acc[h].x * inv[h], acc[h].y * inv[h]);
    }
}

// ---------------- fused gather (post-GEMM L2) + L3 logits: shuffle weights, 1 wave/block, packed ----------------
template <typename TIN, typename TOUT>
__global__ __launch_bounds__(64) void gather_post32_alx_kernel(
    const TIN* __restrict__ h2, const float* __restrict__ als,
    const float* __restrict__ ald, const int* __restrict__ rowptr,
    const int* __restrict__ csr, const float* __restrict__ bias,
    const float* __restrict__ ps3, const float* __restrict__ pd3,
    TOUT* __restrict__ outp,
    float* __restrict__ als3, float* __restrict__ ald3, int N) {
    int wave = blockIdx.x;
    int lane = threadIdx.x;
    if (wave >= N) return;
    int h4 = lane & 3, e4 = lane >> 2;
    int hh = lane >> 4, l16 = lane & 15;
    float aldv = ald[wave * 4 + h4];
    float s = 0.f;
    f32x2 acc = {0.f, 0.f};
    int beg = rowptr[wave], end = rowptr[wave + 1];
    for (int kc = beg; kc < end; kc += 16) {
        int cnt = end - kc;
        if (cnt > 16) cnt = 16;
        int j = kc + e4;
        int src = csr[(j < end) ? j : beg];
        float e = als[src * 4 + h4] + aldv;
        e = fmaxf(e, 0.2f * e);
        float myw = __expf(e);
        if (cnt == 16) {
            int sj[16];
#pragma unroll
            for (int jj = 0; jj < 16; ++jj) sj[jj] = __shfl(src, jj * 4);
            float2 pv[16];
#pragma unroll
            for (int jj = 0; jj < 16; ++jj)
                pv[jj] = ld2(&h2[(size_t)sj[jj] * 128 + hh * 32 + l16 * 2]);
#pragma unroll
            for (int jj = 0; jj < 16; ++jj) {
                float w = __shfl(myw, jj * 4 + hh);
                s += w;
                acc += w * (f32x2){pv[jj].x, pv[jj].y};
            }
        } else {
            for (int jj = 0; jj < cnt; ++jj) {
                int sjj = __shfl(src, jj * 4);
                float w = __shfl(myw, jj * 4 + hh);
                s += w;
                float2 v = ld2(&h2[(size_t)sjj * 128 + hh * 32 + l16 * 2]);
                acc += w * (f32x2){v.x, v.y};
            }
        }
    }
    float inv = 1.f / (s + 1e-16f);
    int c = hh * 32 + l16 * 2;
    float v0 = acc.x * inv + bias[c];
    float v1 = acc.y * inv + bias[c + 1];
    st2(&outp[(size_t)wave * 128 + c], v0, v1);

    // ---- layer-3 logits in-register ----
    float sArr[4], dArr[4];
#pragma unroll
    for (int h = 0; h < 4; ++h) {
        float2 vs = *reinterpret_cast<const float2*>(&ps3[h * 128 + c]);
        float2 vd = *reinterpret_cast<const float2*>(&pd3[h * 128 + c]);
        sArr[h] = v0 * vs.x + v1 * vs.y;
        dArr[h] = v0 * vd.x + v1 * vd.y;
    }
#pragma unroll
    for (int off = 1; off < 64; off <<= 1) {
#pragma unroll
        for (int h = 0; h < 4; ++h) {
            sArr[h] += __shfl_xor(sArr[h], off);
            dArr[h] += __shfl_xor(dArr[h], off);
        }
    }
    if (lane < 4) {
        float os = (lane == 0) ? sArr[0] : (lane == 1) ? sArr[1] : (lane == 2) ? sArr[2] : sArr[3];
        float od = (lane == 0) ? dArr[0] : (lane == 1) ? dArr[1] : (lane == 2) ? dArr[2] : dArr[3];
        als3[wave * 4 + lane] = os;
        ald3[wave * 4 + lane] = od;
    }
}

// ---------------- MFMA GEMM (BM=128 BN=64 BK=32), optional fused col-dot logits ----------------
template <typename TOUT>
__global__ __launch_bounds__(256) void mfma_gemm_kernel(
    const __hip_bfloat16* __restrict__ A, int lda, int aSel,
    const __hip_bfloat16* __restrict__ Bt,
    TOUT* __restrict__ O, int ldo,
    const float* __restrict__ bias,
    const float* __restrict__ a2s, const float* __restrict__ a2d,
    float* __restrict__ oals, float* __restrict__ oald,
    int N, int K) {
    __shared__ __hip_bfloat16 As[128][40];
    __shared__ __hip_bfloat16 Bs[64][40];
    int col0 = blockIdx.x * 64;
    int row0 = blockIdx.y * 128;
    int aOff = aSel ? col0 : 0;
    int tid = threadIdx.x;
    int wv = tid >> 6, lane = tid & 63;
    int g = lane >> 4, l16 = lane & 15;
    f32x4 acc[2][4] = {};

    for (int k0 = 0; k0 < K; k0 += 32) {
#pragma unroll
        for (int i = 0; i < 2; ++i) {
            int idx = tid + i * 256;
            int r = idx >> 2, h4 = idx & 3;
            int gr = row0 + r;
            uint4 v = make_uint4(0, 0, 0, 0);
            if (gr < N) v = *reinterpret_cast<const uint4*>(&A[(size_t)gr * lda + aOff + k0 + h4 * 8]);
            *reinterpret_cast<uint4*>(&As[r][h4 * 8]) = v;
        }
        {
            int r = tid >> 2, h4 = tid & 3;
            uint4 v = *reinterpret_cast<const uint4*>(&Bt[(size_t)(col0 + r) * K + k0 + h4 * 8]);
            *reinterpret_cast<uint4*>(&Bs[r][h4 * 8]) = v;
        }
        __syncthreads();
        s16x8 af[2], bf[4];
#pragma unroll
        for (int m = 0; m < 2; ++m)
            af[m] = *reinterpret_cast<const s16x8*>(&As[wv * 32 + m * 16 + l16][g * 8]);
#pragma unroll
        for (int n = 0; n < 4; ++n)
            bf[n] = *reinterpret_cast<const s16x8*>(&Bs[n * 16 + l16][g * 8]);
#pragma unroll
        for (int m = 0; m < 2; ++m)
#pragma unroll
            for (int n = 0; n < 4; ++n)
                acc[m][n] = __builtin_amdgcn_mfma_f32_16x16x32_bf16(af[m], bf[n], acc[m][n], 0, 0, 0);
        __syncthreads();
    }
#pragma unroll
    for (int m = 0; m < 2; ++m) {
#pragma unroll
        for (int rr = 0; rr < 4; ++rr) {
            int row = row0 + wv * 32 + m * 16 + g * 4 + rr;
            float vv[4];
#pragma unroll
            for (int n = 0; n < 4; ++n) {
                vv[n] = acc[m][n][rr];
                if (bias) vv[n] += bias[col0 + n * 16 + l16];
            }
            if (row < N) {
#pragma unroll
                for (int n = 0; n < 4; ++n)
                    st1(&O[(size_t)row * ldo + col0 + n * 16 + l16], vv[n]);
            }
            if (oals) {
                float ts0 = vv[0] * a2s[col0 + l16]      + vv[1] * a2s[col0 + 16 + l16];
                float ts1 = vv[2] * a2s[col0 + 32 + l16] + vv[3] * a2s[col0 + 48 + l16];
                float td0 = vv[0] * a2d[col0 + l16]      + vv[1] * a2d[col0 + 16 + l16];
                float td1 = vv[2] * a2d[col0 + 32 + l16] + vv[3] * a2d[col0 + 48 + l16];
#pragma unroll
                for (int off = 1; off < 16; off <<= 1) {
                    ts0 += __shfl_xor(ts0, off); ts1 += __shfl_xor(ts1, off);
                    td0 += __shfl_xor(td0, off); td1 += __shfl_xor(td1, off);
                }
                if (l16 == 0 && row < N) {
                    int hb = col0 >> 5;  // heads 2x, 2x+1
                    oals[(size_t)row * 4 + hb]     = ts0;
                    oals[(size_t)row * 4 + hb + 1] = ts1;
                    oald[(size_t)row * 4 + hb]     = td0;
                    oald[(size_t)row * 4 + hb + 1] = td1;
                }
            }
        }
    }
}

// ---------------- launch ----------------
extern "C" void kernel_launch(void* const* d_in, const int* in_sizes, int n_in,
                              void* d_out, int out_size, void* d_ws, size_t ws_size,
                              hipStream_t stream) {
    const float* x      = (const float*)d_in[0];
    const int*   eidx   = (const int*)d_in[1];
    const float* W1     = (const float*)d_in[2];
    const float* a1_src = (const float*)d_in[3];
    const float* a1_dst = (const float*)d_in[4];
    const float* b1     = (const float*)d_in[5];
    const float* W2     = (const float*)d_in[6];
    const float* a2_src = (const float*)d_in[7];
    const float* a2_dst = (const float*)d_in[8];
    const float* b2     = (const float*)d_in[9];
    const float* W3     = (const float*)d_in[10];
    const float* a3_src = (const float*)d_in[11];
    const float* a3_dst = (const float*)d_in[12];
    const float* b3     = (const float*)d_in[13];
    float* out = (float*)d_out;

    const int N = in_sizes[0] / 64;      // 50000
    const int E = in_sizes[1] / 2;       // 800000
    const int NB = (N + 1023) / 1024;

    // ---- workspace ----
    int* rowptr = (int*)d_ws;
    int* deg    = rowptr + (N + 1);
    int* cursor = deg + N;
    int* csr    = cursor + N;
    int* bsum   = csr + E;
    int* boff   = bsum + NB;
    uintptr_t pa = (uintptr_t)(boff + NB);
    pa = (pa + 255) & ~(uintptr_t)255;
    float* als  = (float*)pa;                       // N*4
    float* ald  = als + (size_t)N * 4;              // N*4
    float* als3 = ald + (size_t)N * 4;              // N*4
    float* ald3 = als3 + (size_t)N * 4;             // N*4
    float* ps1  = ald3 + (size_t)N * 4;             // 256
    float* pd1  = ps1 + 256;                        // 256
    float* ps3  = pd1 + 256;                        // 512
    float* pd3  = ps3 + 512;                        // 512
    float* bias12 = pd3 + 512;                      // 128
    __hip_bfloat16* Bt3 = (__hip_bfloat16*)(bias12 + 128);  // 64*512
    __hip_bfloat16* BtF = Bt3 + 64 * 512;                   // 128*256
    uintptr_t pf = (uintptr_t)(BtF + 128 * 256);
    pf = (pf + 255) & ~(uintptr_t)255;
    float* F    = (float*)pf;

    // arena (float units): xb 32N | agg1b 128N | h2b 64N | out2b 64N | agg3 256N = 544N
    __hip_bfloat16* xb    = (__hip_bfloat16*)F;
    __hip_bfloat16* agg1b = (__hip_bfloat16*)(F + (size_t)N * 32);
    __hip_bfloat16* h2b   = (__hip_bfloat16*)(F + (size_t)N * 160);
    __hip_bfloat16* out2b = (__hip_bfloat16*)(F + (size_t)N * 224);
    __hip_bfloat16* agg3  = (__hip_bfloat16*)(F + (size_t)N * 288);

    // ---- CSR build ----
    hipMemsetAsync(deg, 0, (size_t)N * sizeof(int), stream);
    deg_kernel<<<(E + 255) / 256, 256, 0, stream>>>(eidx, deg, E, N);
    reduce_kernel<<<NB, 256, 0, stream>>>(deg, bsum, N);
    scan_bsum_kernel<<<1, 64, 0, stream>>>(bsum, boff, NB, rowptr + N);
    block_scan_kernel<<<NB, 256, 0, stream>>>(deg, boff, rowptr, cursor, N);
    scatter_kernel<<<(E + 255) / 256, 256, 0, stream>>>(eidx, cursor, csr, E, N);

    // ---- prep0 (weights/proj) then x-conv + fused L1 logits ----
    prep0_kernel<<<128 + 128 + 1 + 1 + 2, 256, 0, stream>>>(
        W1, W2, W3, b1, a1_src, a1_dst, a3_src, a3_dst,
        Bt3, BtF, bias12, ps1, pd1, ps3, pd3);
    const int n8 = N * 8;
    xconv_alx_kernel<<<(n8 + 255) / 256, 256, 0, stream>>>(x, ps1, pd1, xb, als, ald, n8);

    const int rowB128 = (N + 127) / 128;

    // ---- layer 1 gather + fused L1L2-GEMM (with fused L2 logits) ----
    gather_pre_kernel<64, __hip_bfloat16, __hip_bfloat16><<<N, 64, 0, stream>>>(
        xb, als, ald, rowptr, csr, agg1b, N);
    mfma_gemm_kernel<__hip_bfloat16><<<dim3(2, rowB128), 256, 0, stream>>>(
        agg1b, 256, 0, BtF, h2b, 128, bias12, a2_src, a2_dst, als, ald, N, 256);

    // ---- layer 2: gather (fused layer-3 logits) ----
    gather_post32_alx_kernel<__hip_bfloat16, __hip_bfloat16><<<N, 64, 0, stream>>>(
        h2b, als, ald, rowptr, csr, b2, ps3, pd3, out2b, als3, ald3, N);

    // ---- layer 3: gather + stacked GEMM (mean folded) ----
    gather_pre_kernel<128, __hip_bfloat16, __hip_bfloat16><<<N, 64, 0, stream>>>(
        out2b, als3, ald3, rowptr, csr, agg3, N);
    mfma_gemm_kernel<float><<<dim3(1, rowB128), 256, 0, stream>>>(
        agg3, 512, 0, Bt3, out, 64, b3, nullptr, nullptr, nullptr, nullptr, N, 512);
}